// Round 3
// baseline (532.786 us; speedup 1.0000x reference)
//
#include <hip/hip_runtime.h>
#include <hip/hip_bf16.h>
#include <stdint.h>

typedef __bf16 bf16x8 __attribute__((ext_vector_type(8)));
typedef float f32x4 __attribute__((ext_vector_type(4)));
typedef unsigned short ushort_t;

#define MFMA16 __builtin_amdgcn_mfma_f32_16x16x32_bf16

static constexpr int Bc = 2, Sc = 2048, Ec = 2048, Hc = 16;

__device__ __forceinline__ void gload16(const void* g, void* l) {
  __builtin_amdgcn_global_load_lds(
      (const __attribute__((address_space(1))) void*)g,
      (__attribute__((address_space(3))) void*)l, 16, 0, 0);
}

__device__ __forceinline__ ushort_t f2bf(float f) {
  uint32_t u = __float_as_uint(f);
  uint32_t r = (u + 0x7fffu + ((u >> 16) & 1u)) >> 16;
  return (ushort_t)r;
}
__device__ __forceinline__ float bf2f(ushort_t u) {
  return __uint_as_float((uint32_t)u << 16);
}

// ---------------- fused casts: all 5 weight/x tensors in one launch ----------------
// ranges (float4 units): x 2097152 | wq 1048576 | wkvu 393216 | wout 1048576 | wkvd(pad 576->640 rows) 327680
__global__ void cast_all(const float* __restrict__ x, const float* __restrict__ Wq,
                         const float* __restrict__ Wkvu, const float* __restrict__ Wout,
                         const float* __restrict__ Wkvd,
                         ushort_t* __restrict__ xb, ushort_t* __restrict__ wq,
                         ushort_t* __restrict__ wkvu, ushort_t* __restrict__ wout,
                         ushort_t* __restrict__ wkvd) {
  int i = blockIdx.x * 256 + threadIdx.x;
  const float* src;
  ushort_t* dst;
  int j;
  if (i < 2097152) { src = x; dst = xb; j = i; }
  else if (i < 3145728) { src = Wq; dst = wq; j = i - 2097152; }
  else if (i < 3538944) { src = Wkvu; dst = wkvu; j = i - 3145728; }
  else if (i < 4587520) { src = Wout; dst = wout; j = i - 3538944; }
  else {
    j = i - 4587520;                      // wkvd with row pad
    int row = j >> 9, col4 = j & 511;
    ushort4 o;
    if (row < 576) {
      float4 v = ((const float4*)Wkvd)[row * 512 + col4];
      o.x = f2bf(v.x); o.y = f2bf(v.y); o.z = f2bf(v.z); o.w = f2bf(v.w);
    } else { o.x = 0; o.y = 0; o.z = 0; o.w = 0; }
    ((ushort4*)wkvd)[j] = o;
    return;
  }
  float4 v = ((const float4*)src)[j];
  ushort4 o;
  o.x = f2bf(v.x); o.y = f2bf(v.y); o.z = f2bf(v.z); o.w = f2bf(v.w);
  ((ushort4*)dst)[j] = o;
}

// ---------------- mask rearrange: m2[q][kb(32)][l16(16)][ni(4)] bf16, pre-multiplied 1/ln2 ----------------
__global__ void mask_rearrange(const float* __restrict__ mask, ushort_t* __restrict__ m2) {
  const float INVLN2 = 1.4426950408889634f;
  int i = blockIdx.x * 256 + threadIdx.x;   // 2048*32*16 = 1048576
  if (i >= 2048 * 32 * 16) return;
  int q = i >> 9, rest = i & 511, kb = rest >> 4, l16 = rest & 15;
  const float* src = mask + (size_t)q * 2048 + kb * 64 + l16;
  ushort4 o;
  o.x = f2bf(src[0] * INVLN2); o.y = f2bf(src[16] * INVLN2);
  o.z = f2bf(src[32] * INVLN2); o.w = f2bf(src[48] * INVLN2);
  ((ushort4*)m2)[i] = o;
}

// ---------------- GEMM: C[m][n] = sum_k A[m][k]*B[n][k], 128x128x32 tiles ----------------
// MODE 0: store bf16. MODE 2: store f32. MODE 1: scatter kv_exp -> vT(swizzled)/kbuf(swizzled).
template<int MODE>
__global__ __launch_bounds__(256, 2)
void gemm_bt(const ushort_t* __restrict__ A, int lda,
             const ushort_t* __restrict__ Bm, int ldb,
             void* __restrict__ Cout, int ldc,
             int M, int N, int K,
             char* __restrict__ vtb, char* __restrict__ kbuf)
{
  __shared__ __align__(16) ushort_t sA[128 * 32];
  __shared__ __align__(16) ushort_t sB[128 * 32];
  int tid = threadIdx.x;
  int nTn = N >> 7;
  int bid = blockIdx.x;
  int chunk = gridDim.x >> 3;                       // grids are %8==0 -> bijective
  bid = (bid & 7) * chunk + (bid >> 3);             // XCD-chunked swizzle
  int tm = bid / nTn, tn = bid - tm * nTn;
  int wave = tid >> 6, lane = tid & 63;
  int wm = (wave >> 1) << 6, wn = (wave & 1) << 6;
  int l16 = lane & 15, g16 = lane >> 4;
  f32x4 acc[4][4] = {};
  int srow = tid >> 2, scol = (tid & 3) << 3;
  const ushort_t* Ag = A + (size_t)(tm * 128 + srow) * lda + scol;
  const ushort_t* Bg = Bm + (size_t)(tn * 128 + srow) * ldb + scol;
  ushort_t* sAp = &sA[srow * 32 + scol];
  ushort_t* sBp = &sB[srow * 32 + scol];
  for (int kt = 0; kt < K; kt += 32) {
    gload16(Ag, sAp);
    gload16(Ag + (size_t)64 * lda, sAp + 64 * 32);
    gload16(Bg, sBp);
    gload16(Bg + (size_t)64 * ldb, sBp + 64 * 32);
    Ag += 32; Bg += 32;
    __syncthreads();
    bf16x8 af[4], bfr[4];
#pragma unroll
    for (int i = 0; i < 4; i++) af[i] = *(const bf16x8*)&sA[(wm + i * 16 + l16) * 32 + g16 * 8];
#pragma unroll
    for (int i = 0; i < 4; i++) bfr[i] = *(const bf16x8*)&sB[(wn + i * 16 + l16) * 32 + g16 * 8];
#pragma unroll
    for (int i = 0; i < 4; i++)
#pragma unroll
      for (int j = 0; j < 4; j++)
        acc[i][j] = MFMA16(af[i], bfr[j], acc[i][j], 0, 0, 0);
    __syncthreads();
  }
  // epilogue: C/D layout col=lane&15, row=(lane>>4)*4+r
#pragma unroll
  for (int i = 0; i < 4; i++) {
#pragma unroll
    for (int j = 0; j < 4; j++) {
#pragma unroll
      for (int r = 0; r < 4; r++) {
        int grow = tm * 128 + wm + i * 16 + g16 * 4 + r;
        int gcol = tn * 128 + wn + j * 16 + l16;
        float v = acc[i][j][r];
        if constexpr (MODE == 0) {
          ((ushort_t*)Cout)[(size_t)grow * ldc + gcol] = f2bf(v);
        } else if constexpr (MODE == 2) {
          ((float*)Cout)[(size_t)grow * ldc + gcol] = v;
        } else {
          int h = gcol / 192, jj = gcol - h * 192;
          int b = grow >> 11, s = grow & 2047;
          size_t bh = (size_t)(b * Hc + h);
          if (jj < 128) {
            // V^T, pre-swizzled for linear staging of 64-col tiles:
            // vT[bh][vd=jj][tile s>>6][128B chunk], elem byte (2*(s&63)) ^ ((vd&7)<<4)
            *(ushort_t*)(vtb + bh * 524288 + (size_t)jj * 4096 + ((s >> 6) * 128) +
                         ((2 * (s & 63)) ^ ((jj & 7) << 4))) = f2bf(v);
          } else {
            int col = 64 + (jj - 128);                    // nope -> k dims 64..127
            *(ushort_t*)(kbuf + (bh * Sc + s) * 256 + ((2 * col) ^ ((s & 7) << 4))) = f2bf(v);
          }
        }
      }
    }
  }
}

// ---------------- broadcast k_rope into kbuf (swizzled byte layout) ----------------
__global__ void rope_fill(const ushort_t* __restrict__ comp, char* __restrict__ kbuf) {
  int i = blockIdx.x * 256 + threadIdx.x;  // over B*S*8 16-byte blocks
  if (i >= Bc * Sc * 8) return;
  int blk = i & 7;
  int m = i >> 3;
  int s = m & 2047, b = m >> 11;
  uint4 v = *(const uint4*)&comp[(size_t)m * 640 + 512 + blk * 8];
  int off = (blk * 16) ^ ((s & 7) << 4);
#pragma unroll
  for (int h = 0; h < Hc; h++) {
    *(uint4*)(kbuf + ((size_t)(b * Hc + h) * Sc + s) * 256 + off) = v;
  }
}

// ---------------- flash attention: block = (b,h,qtile of 64 rows), 4 waves x 16 rows ----------------
// 2 barriers/tile; K/V of tile t+1 reg-prefetched during compute of tile t (T14).
__global__ __launch_bounds__(256, 4)
void attn_kernel(const ushort_t* __restrict__ qb, const char* __restrict__ kbuf,
                 const char* __restrict__ vtb, const ushort_t* __restrict__ m2,
                 ushort_t* __restrict__ attn_o)
{
  __shared__ __align__(16) char smem[40960];
  char* sK = smem;            // 16KB: 64 k-rows x 256B (swizzled)
  char* sV = smem + 16384;    // 16KB: 128 vd-rows x 128B (swizzled)
  char* sP = smem + 32768;    // 8KB: 4 waves x 16 rows x 128B (swizzled)
  const float scale2 = 0.12752081738040466f;  // 128^-0.5 / ln2
  int bid = blockIdx.x;
  bid = (bid & 7) * 128 + (bid >> 3);        // XCD-chunked swizzle (1024 % 8 == 0)
  int qt = bid & 31, bh = bid >> 5;
  int b = bh >> 4, h = bh & 15;
  int tid = threadIdx.x, wave = tid >> 6, lane = tid & 63;
  int l16 = lane & 15, g16 = lane >> 4;

  // Q fragments in registers for the whole kernel (16 rows per wave)
  bf16x8 qf[4];
  {
    int qrow = qt * 64 + wave * 16 + l16;
    const ushort_t* qp = qb + (size_t)(b * Sc + qrow) * 2048 + h * 128 + g16 * 8;
#pragma unroll
    for (int kf = 0; kf < 4; kf++) qf[kf] = *(const bf16x8*)(qp + kf * 32);
  }

  float mrun[4], lrun[4];
#pragma unroll
  for (int r = 0; r < 4; r++) { mrun[r] = -3.0e38f; lrun[r] = 0.f; }
  f32x4 acco[8] = {};

  const char* kg = kbuf + (size_t)bh * Sc * 256;
  const char* vg = vtb + (size_t)bh * 524288;
  char* pB = sP + wave * 2048;

  uint4 kreg[4], vreg[4];
  auto loadT = [&](int kt) {
#pragma unroll
    for (int it = 0; it < 4; it++)
      kreg[it] = *(const uint4*)(kg + kt * 16384 + it * 4096 + tid * 16);
#pragma unroll
    for (int it = 0; it < 4; it++) {
      int l = it * 4096 + tid * 16;
      vreg[it] = *(const uint4*)(vg + (size_t)(l >> 7) * 4096 + kt * 128 + (l & 127));
    }
  };
  auto writeT = [&]() {
#pragma unroll
    for (int it = 0; it < 4; it++)
      *(uint4*)(sK + it * 4096 + tid * 16) = kreg[it];
#pragma unroll
    for (int it = 0; it < 4; it++)
      *(uint4*)(sV + it * 4096 + tid * 16) = vreg[it];
  };

  // prologue: stage tile 0
  loadT(0);
  writeT();
  __syncthreads();

  for (int kt = 0; kt < 32; kt++) {
    if (kt < 31) loadT(kt + 1);   // prefetch issue — lands after post-PV barrier

    // scores: sc[ni] = Q(16 rows) . K(64)^T
    f32x4 sc[4] = {};
    __builtin_amdgcn_s_setprio(1);
#pragma unroll
    for (int ni = 0; ni < 4; ni++) {
#pragma unroll
      for (int kf = 0; kf < 4; kf++) {
        bf16x8 kfr = *(const bf16x8*)(sK + (ni * 16 + l16) * 256 +
                                      ((kf * 64 + g16 * 16) ^ ((l16 & 7) << 4)));
        sc[ni] = MFMA16(qf[kf], kfr, sc[ni], 0, 0, 0);
      }
    }
    __builtin_amdgcn_s_setprio(0);

    // online softmax in exp2 domain (row = g16*4+r, cols = ni*16+l16)
#pragma unroll
    for (int r = 0; r < 4; r++) {
      int q = qt * 64 + wave * 16 + g16 * 4 + r;
      ushort4 mv = ((const ushort4*)m2)[(q * 32 + kt) * 16 + l16];
      sc[0][r] = sc[0][r] * scale2 + bf2f(mv.x);
      sc[1][r] = sc[1][r] * scale2 + bf2f(mv.y);
      sc[2][r] = sc[2][r] * scale2 + bf2f(mv.z);
      sc[3][r] = sc[3][r] * scale2 + bf2f(mv.w);
    }
    float mx[4];
#pragma unroll
    for (int r = 0; r < 4; r++) {
      float m0 = fmaxf(fmaxf(sc[0][r], sc[1][r]), fmaxf(sc[2][r], sc[3][r]));
#pragma unroll
      for (int m = 1; m < 16; m <<= 1) m0 = fmaxf(m0, __shfl_xor(m0, m));
      mx[r] = m0;
    }
    bool ok = true;
#pragma unroll
    for (int r = 0; r < 4; r++) ok &= (mx[r] <= mrun[r] + 11.0f);
    if (!__all(ok)) {   // rescale path (rare): T13 defer-max
#pragma unroll
      for (int r = 0; r < 4; r++) {
        float mnew = fmaxf(mrun[r], mx[r]);
        float corr = __builtin_amdgcn_exp2f(mrun[r] - mnew);
        lrun[r] *= corr;
        mrun[r] = mnew;
#pragma unroll
        for (int ni = 0; ni < 8; ni++) acco[ni][r] *= corr;
      }
    }
#pragma unroll
    for (int r = 0; r < 4; r++) {
      int rowl = g16 * 4 + r;
      char* pb = pB + rowl * 128;
      int sx = (rowl & 7) << 4;
      float rs = 0.f;
#pragma unroll
      for (int ni = 0; ni < 4; ni++) {
        float p = __builtin_amdgcn_exp2f(sc[ni][r] - mrun[r]);
        rs += p;
        *(ushort_t*)(pb + ((2 * (ni * 16 + l16)) ^ sx)) = f2bf(p);
      }
      lrun[r] += rs;     // lane-partial; reduced across l16 in epilogue
    }

    // PV: acco += P(16x64) . V(64x128)   (P wave-private -> no barrier)
    __builtin_amdgcn_s_setprio(1);
#pragma unroll
    for (int kf = 0; kf < 2; kf++) {
      bf16x8 pa = *(const bf16x8*)(pB + l16 * 128 +
                                   ((kf * 64 + g16 * 16) ^ ((l16 & 7) << 4)));
#pragma unroll
      for (int ni = 0; ni < 8; ni++) {
        bf16x8 vf = *(const bf16x8*)(sV + (ni * 16 + l16) * 128 +
                                     ((kf * 64 + g16 * 16) ^ ((l16 & 7) << 4)));
        acco[ni] = MFMA16(pa, vf, acco[ni], 0, 0, 0);
      }
    }
    __builtin_amdgcn_s_setprio(0);

    __syncthreads();               // all waves done reading sK/sV
    if (kt < 31) writeT();         // prefetched regs -> LDS (vmcnt wait auto)
    __syncthreads();               // staged tile visible to all
  }

  // epilogue: reduce lane-partial l across 16 lanes, then O = acco / l
#pragma unroll
  for (int r = 0; r < 4; r++) {
#pragma unroll
    for (int m = 1; m < 16; m <<= 1) lrun[r] += __shfl_xor(lrun[r], m);
  }
#pragma unroll
  for (int ni = 0; ni < 8; ni++) {
#pragma unroll
    for (int r = 0; r < 4; r++) {
      int qrow = qt * 64 + wave * 16 + g16 * 4 + r;
      int col = ni * 16 + l16;
      float o = acco[ni][r] / lrun[r];
      attn_o[(size_t)(b * Sc + qrow) * 2048 + h * 128 + col] = f2bf(o);
    }
  }
}

extern "C" void kernel_launch(void* const* d_in, const int* in_sizes, int n_in,
                              void* d_out, int out_size, void* d_ws, size_t ws_size,
                              hipStream_t stream) {
  const float* x    = (const float*)d_in[0];
  const float* mask = (const float*)d_in[1];
  const float* Wkvd = (const float*)d_in[2];
  const float* Wkvu = (const float*)d_in[3];
  const float* Wq   = (const float*)d_in[4];
  const float* Wout = (const float*)d_in[5];

  char* ws = (char*)d_ws;
  size_t off = 0;
  auto alloc = [&](size_t bytes) { char* p = ws + off; off += (bytes + 255) & ~(size_t)255; return p; };
  ushort_t* xb   = (ushort_t*)alloc((size_t)4096 * 2048 * 2);
  ushort_t* wkvd = (ushort_t*)alloc((size_t)640 * 2048 * 2);
  ushort_t* wq   = (ushort_t*)alloc((size_t)2048 * 2048 * 2);
  ushort_t* wkvu = (ushort_t*)alloc((size_t)3072 * 512 * 2);
  ushort_t* wout = (ushort_t*)alloc((size_t)2048 * 2048 * 2);
  ushort_t* comp = (ushort_t*)alloc((size_t)4096 * 640 * 2);
  ushort_t* qbuf = (ushort_t*)alloc((size_t)4096 * 2048 * 2);
  char*     kbuf = alloc((size_t)Bc * Hc * Sc * 256);
  char*     vtb  = alloc((size_t)Bc * Hc * 524288);
  ushort_t* attn_o = xb;   // xb dead after q-GEMM; reuse
  ushort_t* m2 = wq;       // wq dead after q-GEMM; reuse (8MB)

  // all casts in one launch
  cast_all<<<19200, 256, 0, stream>>>(x, Wq, Wkvu, Wout, Wkvd, xb, wq, wkvu, wout, wkvd);

  // compressed = x . W_kv_down^T  (N padded 576->640)
  gemm_bt<0><<<32 * 5, 256, 0, stream>>>(xb, 2048, wkvd, 2048, comp, 640, 4096, 640, 2048, nullptr, nullptr);
  // q = x . W_q^T
  gemm_bt<0><<<32 * 16, 256, 0, stream>>>(xb, 2048, wq, 2048, qbuf, 2048, 4096, 2048, 2048, nullptr, nullptr);
  // mask -> fragment-ordered bf16 * (1/ln2)  (after q-GEMM: m2 overlays wq)
  mask_rearrange<<<4096, 256, 0, stream>>>(mask, m2);
  // kv_exp = kv_c . W_kv_up^T, scattered into vT(swizzled) + kbuf(nope, swizzled)
  gemm_bt<1><<<32 * 24, 256, 0, stream>>>(comp, 640, wkvu, 512, nullptr, 0, 4096, 3072, 512, vtb, kbuf);
  // k_rope broadcast into kbuf (swizzled)
  rope_fill<<<32768 / 256, 256, 0, stream>>>(comp, kbuf);
  // flash attention
  attn_kernel<<<1024, 256, 0, stream>>>(qbuf, kbuf, vtb, m2, attn_o);
  // out = attn . W_out^T (fp32 store)
  gemm_bt<2><<<32 * 16, 256, 0, stream>>>(attn_o, 2048, wout, 2048, d_out, 2048, 4096, 2048, 2048, nullptr, nullptr);
}

// Round 4
// 321.171 us; speedup vs baseline: 1.6589x; 1.6589x over previous
//
#include <hip/hip_runtime.h>
#include <hip/hip_bf16.h>
#include <stdint.h>

typedef __bf16 bf16x8 __attribute__((ext_vector_type(8)));
typedef float f32x4 __attribute__((ext_vector_type(4)));
typedef unsigned short ushort_t;

#define MFMA16 __builtin_amdgcn_mfma_f32_16x16x32_bf16

static constexpr int Bc = 2, Sc = 2048, Ec = 2048, Hc = 16;

__device__ __forceinline__ void gload16(const void* g, void* l) {
  __builtin_amdgcn_global_load_lds(
      (const __attribute__((address_space(1))) void*)g,
      (__attribute__((address_space(3))) void*)l, 16, 0, 0);
}

__device__ __forceinline__ ushort_t f2bf(float f) {
  uint32_t u = __float_as_uint(f);
  uint32_t r = (u + 0x7fffu + ((u >> 16) & 1u)) >> 16;
  return (ushort_t)r;
}
__device__ __forceinline__ float bf2f(ushort_t u) {
  return __uint_as_float((uint32_t)u << 16);
}

// ---------------- fused casts: all 5 weight/x tensors in one launch ----------------
__global__ void cast_all(const float* __restrict__ x, const float* __restrict__ Wq,
                         const float* __restrict__ Wkvu, const float* __restrict__ Wout,
                         const float* __restrict__ Wkvd,
                         ushort_t* __restrict__ xb, ushort_t* __restrict__ wq,
                         ushort_t* __restrict__ wkvu, ushort_t* __restrict__ wout,
                         ushort_t* __restrict__ wkvd) {
  int i = blockIdx.x * 256 + threadIdx.x;
  const float* src;
  ushort_t* dst;
  int j;
  if (i < 2097152) { src = x; dst = xb; j = i; }
  else if (i < 3145728) { src = Wq; dst = wq; j = i - 2097152; }
  else if (i < 3538944) { src = Wkvu; dst = wkvu; j = i - 3145728; }
  else if (i < 4587520) { src = Wout; dst = wout; j = i - 3538944; }
  else {
    j = i - 4587520;                      // wkvd with row pad 576->640
    int row = j >> 9, col4 = j & 511;
    ushort4 o;
    if (row < 576) {
      float4 v = ((const float4*)Wkvd)[row * 512 + col4];
      o.x = f2bf(v.x); o.y = f2bf(v.y); o.z = f2bf(v.z); o.w = f2bf(v.w);
    } else { o.x = 0; o.y = 0; o.z = 0; o.w = 0; }
    ((ushort4*)wkvd)[j] = o;
    return;
  }
  float4 v = ((const float4*)src)[j];
  ushort4 o;
  o.x = f2bf(v.x); o.y = f2bf(v.y); o.z = f2bf(v.z); o.w = f2bf(v.w);
  ((ushort4*)dst)[j] = o;
}

// ---------------- mask rearrange: m2[q][kb(32)][l16(16)][ni(4)] bf16, pre-multiplied 1/ln2 ----------------
__global__ void mask_rearrange(const float* __restrict__ mask, ushort_t* __restrict__ m2) {
  const float INVLN2 = 1.4426950408889634f;
  int i = blockIdx.x * 256 + threadIdx.x;   // 2048*32*16 = 1048576
  if (i >= 2048 * 32 * 16) return;
  int q = i >> 9, rest = i & 511, kb = rest >> 4, l16 = rest & 15;
  const float* src = mask + (size_t)q * 2048 + kb * 64 + l16;
  ushort4 o;
  o.x = f2bf(src[0] * INVLN2); o.y = f2bf(src[16] * INVLN2);
  o.z = f2bf(src[32] * INVLN2); o.w = f2bf(src[48] * INVLN2);
  ((ushort4*)m2)[i] = o;
}

// ---------------- GEMM: C[m][n] = sum_k A[m][k]*B[n][k], 128x128x32 tiles ----------------
template<int MODE>
__global__ __launch_bounds__(256, 2)
void gemm_bt(const ushort_t* __restrict__ A, int lda,
             const ushort_t* __restrict__ Bm, int ldb,
             void* __restrict__ Cout, int ldc,
             int M, int N, int K,
             char* __restrict__ vtb, char* __restrict__ kbuf)
{
  __shared__ __align__(16) ushort_t sA[128 * 32];
  __shared__ __align__(16) ushort_t sB[128 * 32];
  int tid = threadIdx.x;
  int nTn = N >> 7;
  int bid = blockIdx.x;
  int chunk = gridDim.x >> 3;                       // grids are %8==0 -> bijective
  bid = (bid & 7) * chunk + (bid >> 3);             // XCD-chunked swizzle
  int tm = bid / nTn, tn = bid - tm * nTn;
  int wave = tid >> 6, lane = tid & 63;
  int wm = (wave >> 1) << 6, wn = (wave & 1) << 6;
  int l16 = lane & 15, g16 = lane >> 4;
  f32x4 acc[4][4] = {};
  int srow = tid >> 2, scol = (tid & 3) << 3;
  const ushort_t* Ag = A + (size_t)(tm * 128 + srow) * lda + scol;
  const ushort_t* Bg = Bm + (size_t)(tn * 128 + srow) * ldb + scol;
  ushort_t* sAp = &sA[srow * 32 + scol];
  ushort_t* sBp = &sB[srow * 32 + scol];
  for (int kt = 0; kt < K; kt += 32) {
    gload16(Ag, sAp);
    gload16(Ag + (size_t)64 * lda, sAp + 64 * 32);
    gload16(Bg, sBp);
    gload16(Bg + (size_t)64 * ldb, sBp + 64 * 32);
    Ag += 32; Bg += 32;
    __syncthreads();
    bf16x8 af[4], bfr[4];
#pragma unroll
    for (int i = 0; i < 4; i++) af[i] = *(const bf16x8*)&sA[(wm + i * 16 + l16) * 32 + g16 * 8];
#pragma unroll
    for (int i = 0; i < 4; i++) bfr[i] = *(const bf16x8*)&sB[(wn + i * 16 + l16) * 32 + g16 * 8];
#pragma unroll
    for (int i = 0; i < 4; i++)
#pragma unroll
      for (int j = 0; j < 4; j++)
        acc[i][j] = MFMA16(af[i], bfr[j], acc[i][j], 0, 0, 0);
    __syncthreads();
  }
  // epilogue: C/D layout col=lane&15, row=(lane>>4)*4+r
#pragma unroll
  for (int i = 0; i < 4; i++) {
#pragma unroll
    for (int j = 0; j < 4; j++) {
#pragma unroll
      for (int r = 0; r < 4; r++) {
        int grow = tm * 128 + wm + i * 16 + g16 * 4 + r;
        int gcol = tn * 128 + wn + j * 16 + l16;
        float v = acc[i][j][r];
        if constexpr (MODE == 0) {
          ((ushort_t*)Cout)[(size_t)grow * ldc + gcol] = f2bf(v);
        } else if constexpr (MODE == 2) {
          ((float*)Cout)[(size_t)grow * ldc + gcol] = v;
        } else {
          int h = gcol / 192, jj = gcol - h * 192;
          int b = grow >> 11, s = grow & 2047;
          size_t bh = (size_t)(b * Hc + h);
          if (jj < 128) {
            // V^T, pre-swizzled for linear staging of 64-col tiles
            *(ushort_t*)(vtb + bh * 524288 + (size_t)jj * 4096 + ((s >> 6) * 128) +
                         ((2 * (s & 63)) ^ ((jj & 7) << 4))) = f2bf(v);
          } else {
            int col = 64 + (jj - 128);                    // nope -> k dims 64..127
            *(ushort_t*)(kbuf + (bh * Sc + s) * 256 + ((2 * col) ^ ((s & 7) << 4))) = f2bf(v);
          }
        }
      }
    }
  }
}

// ---------------- broadcast k_rope into kbuf (swizzled byte layout) ----------------
__global__ void rope_fill(const ushort_t* __restrict__ comp, char* __restrict__ kbuf) {
  int i = blockIdx.x * 256 + threadIdx.x;  // over B*S*8 16-byte blocks
  if (i >= Bc * Sc * 8) return;
  int blk = i & 7;
  int m = i >> 3;
  int s = m & 2047, b = m >> 11;
  uint4 v = *(const uint4*)&comp[(size_t)m * 640 + 512 + blk * 8];
  int off = (blk * 16) ^ ((s & 7) << 4);
#pragma unroll
  for (int h = 0; h < Hc; h++) {
    *(uint4*)(kbuf + ((size_t)(b * Hc + h) * Sc + s) * 256 + off) = v;
  }
}

// ---------------- flash attention: block = (b,h,qtile of 64 rows), 4 waves x 16 rows ----------------
// gload16 direct staging (round-2 structure), dedicated sP -> 2 barriers/tile,
// exp2-domain softmax with deferred l-sum + defer-max (T13), setprio (T5).
__global__ __launch_bounds__(256, 4)
void attn_kernel(const ushort_t* __restrict__ qb, const char* __restrict__ kbuf,
                 const char* __restrict__ vtb, const ushort_t* __restrict__ m2,
                 ushort_t* __restrict__ attn_o)
{
  __shared__ __align__(16) char smem[40960];
  char* sK = smem;            // 16KB: 64 k-rows x 256B (swizzled)
  char* sV = smem + 16384;    // 16KB: 128 vd-rows x 128B (swizzled)
  char* sP = smem + 32768;    // 8KB: 4 waves x 16 rows x 128B (swizzled)
  const float scale2 = 0.12752081738040466f;  // 128^-0.5 / ln2
  int bid = blockIdx.x;
  bid = (bid & 7) * 128 + (bid >> 3);        // XCD-chunked swizzle (1024 % 8 == 0)
  int qt = bid & 31, bh = bid >> 5;
  int b = bh >> 4, h = bh & 15;
  int tid = threadIdx.x, wave = tid >> 6, lane = tid & 63;
  int l16 = lane & 15, g16 = lane >> 4;

  // Q fragments in registers for the whole kernel (16 rows per wave)
  bf16x8 qf[4];
  {
    int qrow = qt * 64 + wave * 16 + l16;
    const ushort_t* qp = qb + (size_t)(b * Sc + qrow) * 2048 + h * 128 + g16 * 8;
#pragma unroll
    for (int kf = 0; kf < 4; kf++) qf[kf] = *(const bf16x8*)(qp + kf * 32);
  }

  float mrun[4], lrun[4];
#pragma unroll
  for (int r = 0; r < 4; r++) { mrun[r] = -3.0e38f; lrun[r] = 0.f; }
  f32x4 acco[8] = {};

  const char* kg = kbuf + (size_t)bh * Sc * 256;
  const char* vg = vtb + (size_t)bh * 524288;
  char* pB = sP + wave * 2048;

  for (int kt = 0; kt < 32; kt++) {
    // stage K tile: 16KB linear (global bytes pre-swizzled)
#pragma unroll
    for (int it = 0; it < 4; it++)
      gload16(kg + kt * 16384 + it * 4096 + tid * 16, sK + it * 4096 + tid * 16);
    // stage V^T tile: 16KB, per-vd-row 128B chunks (global bytes pre-swizzled)
#pragma unroll
    for (int it = 0; it < 4; it++) {
      int l = it * 4096 + tid * 16;
      gload16(vg + (size_t)(l >> 7) * 4096 + kt * 128 + (l & 127), sV + l);
    }
    __syncthreads();   // compiler drains vmcnt before barrier -> tiles visible

    // scores: sc[ni] = Q(16 rows) . K(64)^T
    f32x4 sc[4] = {};
    __builtin_amdgcn_s_setprio(1);
#pragma unroll
    for (int ni = 0; ni < 4; ni++) {
#pragma unroll
      for (int kf = 0; kf < 4; kf++) {
        bf16x8 kfr = *(const bf16x8*)(sK + (ni * 16 + l16) * 256 +
                                      ((kf * 64 + g16 * 16) ^ ((l16 & 7) << 4)));
        sc[ni] = MFMA16(qf[kf], kfr, sc[ni], 0, 0, 0);
      }
    }
    __builtin_amdgcn_s_setprio(0);

    // online softmax in exp2 domain (row = g16*4+r, cols = ni*16+l16)
#pragma unroll
    for (int r = 0; r < 4; r++) {
      int q = qt * 64 + wave * 16 + g16 * 4 + r;
      ushort4 mv = ((const ushort4*)m2)[(q * 32 + kt) * 16 + l16];
      sc[0][r] = sc[0][r] * scale2 + bf2f(mv.x);
      sc[1][r] = sc[1][r] * scale2 + bf2f(mv.y);
      sc[2][r] = sc[2][r] * scale2 + bf2f(mv.z);
      sc[3][r] = sc[3][r] * scale2 + bf2f(mv.w);
    }
    float mx[4];
#pragma unroll
    for (int r = 0; r < 4; r++) {
      float m0 = fmaxf(fmaxf(sc[0][r], sc[1][r]), fmaxf(sc[2][r], sc[3][r]));
#pragma unroll
      for (int m = 1; m < 16; m <<= 1) m0 = fmaxf(m0, __shfl_xor(m0, m));
      mx[r] = m0;
    }
    bool ok = true;
#pragma unroll
    for (int r = 0; r < 4; r++) ok &= (mx[r] <= mrun[r] + 11.0f);
    if (!__all(ok)) {   // rescale path (rare): T13 defer-max
#pragma unroll
      for (int r = 0; r < 4; r++) {
        float mnew = fmaxf(mrun[r], mx[r]);
        float corr = __builtin_amdgcn_exp2f(mrun[r] - mnew);
        lrun[r] *= corr;
        mrun[r] = mnew;
#pragma unroll
        for (int ni = 0; ni < 8; ni++) acco[ni][r] *= corr;
      }
    }
#pragma unroll
    for (int r = 0; r < 4; r++) {
      int rowl = g16 * 4 + r;
      char* pb = pB + rowl * 128;
      int sx = (rowl & 7) << 4;
      float rs = 0.f;
#pragma unroll
      for (int ni = 0; ni < 4; ni++) {
        float p = __builtin_amdgcn_exp2f(sc[ni][r] - mrun[r]);
        rs += p;
        *(ushort_t*)(pb + ((2 * (ni * 16 + l16)) ^ sx)) = f2bf(p);
      }
      lrun[r] += rs;     // lane-partial; reduced across l16 in epilogue
    }

    // PV: acco += P(16x64) . V(64x128)   (P wave-private -> no barrier)
    __builtin_amdgcn_s_setprio(1);
#pragma unroll
    for (int kf = 0; kf < 2; kf++) {
      bf16x8 pa = *(const bf16x8*)(pB + l16 * 128 +
                                   ((kf * 64 + g16 * 16) ^ ((l16 & 7) << 4)));
#pragma unroll
      for (int ni = 0; ni < 8; ni++) {
        bf16x8 vf = *(const bf16x8*)(sV + (ni * 16 + l16) * 128 +
                                     ((kf * 64 + g16 * 16) ^ ((l16 & 7) << 4)));
        acco[ni] = MFMA16(pa, vf, acco[ni], 0, 0, 0);
      }
    }
    __builtin_amdgcn_s_setprio(0);

    __syncthreads();   // all waves done reading sK/sV before next stage
  }

  // epilogue: reduce lane-partial l across 16 lanes, then O = acco / l
#pragma unroll
  for (int r = 0; r < 4; r++) {
#pragma unroll
    for (int m = 1; m < 16; m <<= 1) lrun[r] += __shfl_xor(lrun[r], m);
  }
#pragma unroll
  for (int ni = 0; ni < 8; ni++) {
#pragma unroll
    for (int r = 0; r < 4; r++) {
      int qrow = qt * 64 + wave * 16 + g16 * 4 + r;
      int col = ni * 16 + l16;
      float o = acco[ni][r] / lrun[r];
      attn_o[(size_t)(b * Sc + qrow) * 2048 + h * 128 + col] = f2bf(o);
    }
  }
}

extern "C" void kernel_launch(void* const* d_in, const int* in_sizes, int n_in,
                              void* d_out, int out_size, void* d_ws, size_t ws_size,
                              hipStream_t stream) {
  const float* x    = (const float*)d_in[0];
  const float* mask = (const float*)d_in[1];
  const float* Wkvd = (const float*)d_in[2];
  const float* Wkvu = (const float*)d_in[3];
  const float* Wq   = (const float*)d_in[4];
  const float* Wout = (const float*)d_in[5];

  char* ws = (char*)d_ws;
  size_t off = 0;
  auto alloc = [&](size_t bytes) { char* p = ws + off; off += (bytes + 255) & ~(size_t)255; return p; };
  ushort_t* xb   = (ushort_t*)alloc((size_t)4096 * 2048 * 2);
  ushort_t* wkvd = (ushort_t*)alloc((size_t)640 * 2048 * 2);
  ushort_t* wq   = (ushort_t*)alloc((size_t)2048 * 2048 * 2);
  ushort_t* wkvu = (ushort_t*)alloc((size_t)3072 * 512 * 2);
  ushort_t* wout = (ushort_t*)alloc((size_t)2048 * 2048 * 2);
  ushort_t* comp = (ushort_t*)alloc((size_t)4096 * 640 * 2);
  ushort_t* qbuf = (ushort_t*)alloc((size_t)4096 * 2048 * 2);
  char*     kbuf = alloc((size_t)Bc * Hc * Sc * 256);
  char*     vtb  = alloc((size_t)Bc * Hc * 524288);
  ushort_t* attn_o = xb;   // xb dead after q-GEMM; reuse
  ushort_t* m2 = wq;       // wq dead after q-GEMM; reuse (8MB)

  // all casts in one launch
  cast_all<<<19200, 256, 0, stream>>>(x, Wq, Wkvu, Wout, Wkvd, xb, wq, wkvu, wout, wkvd);

  // compressed = x . W_kv_down^T  (N padded 576->640)
  gemm_bt<0><<<32 * 5, 256, 0, stream>>>(xb, 2048, wkvd, 2048, comp, 640, 4096, 640, 2048, nullptr, nullptr);
  // q = x . W_q^T
  gemm_bt<0><<<32 * 16, 256, 0, stream>>>(xb, 2048, wq, 2048, qbuf, 2048, 4096, 2048, 2048, nullptr, nullptr);
  // mask -> fragment-ordered bf16 * (1/ln2)  (after q-GEMM: m2 overlays wq)
  mask_rearrange<<<4096, 256, 0, stream>>>(mask, m2);
  // kv_exp = kv_c . W_kv_up^T, scattered into vT(swizzled) + kbuf(nope, swizzled)
  gemm_bt<1><<<32 * 24, 256, 0, stream>>>(comp, 640, wkvu, 512, nullptr, 0, 4096, 3072, 512, vtb, kbuf);
  // k_rope broadcast into kbuf (swizzled)
  rope_fill<<<32768 / 256, 256, 0, stream>>>(comp, kbuf);
  // flash attention
  attn_kernel<<<1024, 256, 0, stream>>>(qbuf, kbuf, vtb, m2, attn_o);
  // out = attn . W_out^T (fp32 store)
  gemm_bt<2><<<32 * 16, 256, 0, stream>>>(attn_o, 2048, wout, 2048, d_out, 2048, 4096, 2048, 2048, nullptr, nullptr);
}

// Round 5
// 294.152 us; speedup vs baseline: 1.8113x; 1.0919x over previous
//
#include <hip/hip_runtime.h>
#include <hip/hip_bf16.h>
#include <stdint.h>

typedef __bf16 bf16x8 __attribute__((ext_vector_type(8)));
typedef float f32x4 __attribute__((ext_vector_type(4)));
typedef unsigned short ushort_t;
typedef unsigned short ushort8v __attribute__((ext_vector_type(8)));

#define MFMA16 __builtin_amdgcn_mfma_f32_16x16x32_bf16

static constexpr int Bc = 2, Sc = 2048, Ec = 2048, Hc = 16;

__device__ __forceinline__ void gload16(const void* g, void* l) {
  __builtin_amdgcn_global_load_lds(
      (const __attribute__((address_space(1))) void*)g,
      (__attribute__((address_space(3))) void*)l, 16, 0, 0);
}

__device__ __forceinline__ ushort_t f2bf(float f) {
  uint32_t u = __float_as_uint(f);
  uint32_t r = (u + 0x7fffu + ((u >> 16) & 1u)) >> 16;
  return (ushort_t)r;
}
__device__ __forceinline__ float bf2f(ushort_t u) {
  return __uint_as_float((uint32_t)u << 16);
}
__device__ __forceinline__ uint32_t cvtpk(float a, float b) {
  uint32_t d;
  asm("v_cvt_pk_bf16_f32 %0, %1, %2" : "=v"(d) : "v"(a), "v"(b));
  return d;
}

// ---------------- fused casts: all 5 weight/x tensors in one launch ----------------
__global__ void cast_all(const float* __restrict__ x, const float* __restrict__ Wq,
                         const float* __restrict__ Wkvu, const float* __restrict__ Wout,
                         const float* __restrict__ Wkvd,
                         ushort_t* __restrict__ xb, ushort_t* __restrict__ wq,
                         ushort_t* __restrict__ wkvu, ushort_t* __restrict__ wout,
                         ushort_t* __restrict__ wkvd) {
  int i = blockIdx.x * 256 + threadIdx.x;
  const float* src;
  ushort_t* dst;
  int j;
  if (i < 2097152) { src = x; dst = xb; j = i; }
  else if (i < 3145728) { src = Wq; dst = wq; j = i - 2097152; }
  else if (i < 3538944) { src = Wkvu; dst = wkvu; j = i - 3145728; }
  else if (i < 4587520) { src = Wout; dst = wout; j = i - 3538944; }
  else {
    j = i - 4587520;                      // wkvd with row pad 576->640
    int row = j >> 9, col4 = j & 511;
    ushort4 o;
    if (row < 576) {
      float4 v = ((const float4*)Wkvd)[row * 512 + col4];
      o.x = f2bf(v.x); o.y = f2bf(v.y); o.z = f2bf(v.z); o.w = f2bf(v.w);
    } else { o.x = 0; o.y = 0; o.z = 0; o.w = 0; }
    ((ushort4*)wkvd)[j] = o;
    return;
  }
  float4 v = ((const float4*)src)[j];
  ushort4 o;
  o.x = f2bf(v.x); o.y = f2bf(v.y); o.z = f2bf(v.z); o.w = f2bf(v.w);
  ((ushort4*)dst)[j] = o;
}

// ---------------- mask rearrange for SWAPPED layout ----------------
// m3 ushort8 index = ((q*32+kt)*4+g)*2+half ; element j = ni_local*4+r (ni = half*2+ni_local)
// value = mask[q][kt*64 + ni*16 + g*4 + r] * (1/ln2)
__global__ void mask_rearrange(const float* __restrict__ mask, ushort_t* __restrict__ m3) {
  const float INVLN2 = 1.4426950408889634f;
  int i = blockIdx.x * 256 + threadIdx.x;   // 2048*32*4*2 = 524288
  if (i >= 524288) return;
  int half = i & 1, g = (i >> 1) & 3, kt = (i >> 3) & 31, q = i >> 8;
  const float* s0 = mask + (size_t)q * 2048 + kt * 64 + half * 32 + g * 4;
  float4 a = *(const float4*)s0;          // ni = half*2,   r=0..3
  float4 c = *(const float4*)(s0 + 16);   // ni = half*2+1, r=0..3
  ushort8v o;
  o[0] = f2bf(a.x * INVLN2); o[1] = f2bf(a.y * INVLN2);
  o[2] = f2bf(a.z * INVLN2); o[3] = f2bf(a.w * INVLN2);
  o[4] = f2bf(c.x * INVLN2); o[5] = f2bf(c.y * INVLN2);
  o[6] = f2bf(c.z * INVLN2); o[7] = f2bf(c.w * INVLN2);
  ((ushort8v*)m3)[i] = o;
}

// ---------------- GEMM: C[m][n] = sum_k A[m][k]*B[n][k], 128x128x32 tiles ----------------
template<int MODE>
__global__ __launch_bounds__(256, 2)
void gemm_bt(const ushort_t* __restrict__ A, int lda,
             const ushort_t* __restrict__ Bm, int ldb,
             void* __restrict__ Cout, int ldc,
             int M, int N, int K,
             char* __restrict__ vtb, char* __restrict__ kbuf)
{
  __shared__ __align__(16) ushort_t sA[128 * 32];
  __shared__ __align__(16) ushort_t sB[128 * 32];
  int tid = threadIdx.x;
  int nTn = N >> 7;
  int bid = blockIdx.x;
  int chunk = gridDim.x >> 3;                       // grids are %8==0 -> bijective
  bid = (bid & 7) * chunk + (bid >> 3);             // XCD-chunked swizzle
  int tm = bid / nTn, tn = bid - tm * nTn;
  int wave = tid >> 6, lane = tid & 63;
  int wm = (wave >> 1) << 6, wn = (wave & 1) << 6;
  int l16 = lane & 15, g16 = lane >> 4;
  f32x4 acc[4][4] = {};
  int srow = tid >> 2, scol = (tid & 3) << 3;
  const ushort_t* Ag = A + (size_t)(tm * 128 + srow) * lda + scol;
  const ushort_t* Bg = Bm + (size_t)(tn * 128 + srow) * ldb + scol;
  ushort_t* sAp = &sA[srow * 32 + scol];
  ushort_t* sBp = &sB[srow * 32 + scol];
  for (int kt = 0; kt < K; kt += 32) {
    gload16(Ag, sAp);
    gload16(Ag + (size_t)64 * lda, sAp + 64 * 32);
    gload16(Bg, sBp);
    gload16(Bg + (size_t)64 * ldb, sBp + 64 * 32);
    Ag += 32; Bg += 32;
    __syncthreads();
    bf16x8 af[4], bfr[4];
#pragma unroll
    for (int i = 0; i < 4; i++) af[i] = *(const bf16x8*)&sA[(wm + i * 16 + l16) * 32 + g16 * 8];
#pragma unroll
    for (int i = 0; i < 4; i++) bfr[i] = *(const bf16x8*)&sB[(wn + i * 16 + l16) * 32 + g16 * 8];
#pragma unroll
    for (int i = 0; i < 4; i++)
#pragma unroll
      for (int j = 0; j < 4; j++)
        acc[i][j] = MFMA16(af[i], bfr[j], acc[i][j], 0, 0, 0);
    __syncthreads();
  }
  // epilogue: C/D layout col=lane&15, row=(lane>>4)*4+r
#pragma unroll
  for (int i = 0; i < 4; i++) {
#pragma unroll
    for (int j = 0; j < 4; j++) {
#pragma unroll
      for (int r = 0; r < 4; r++) {
        int grow = tm * 128 + wm + i * 16 + g16 * 4 + r;
        int gcol = tn * 128 + wn + j * 16 + l16;
        float v = acc[i][j][r];
        if constexpr (MODE == 0) {
          ((ushort_t*)Cout)[(size_t)grow * ldc + gcol] = f2bf(v);
        } else if constexpr (MODE == 2) {
          ((float*)Cout)[(size_t)grow * ldc + gcol] = v;
        } else {
          int h = gcol / 192, jj = gcol - h * 192;
          int b = grow >> 11, s = grow & 2047;
          size_t bh = (size_t)(b * Hc + h);
          if (jj < 128) {
            // V^T, pre-swizzled for linear staging of 64-col tiles
            *(ushort_t*)(vtb + bh * 524288 + (size_t)jj * 4096 + ((s >> 6) * 128) +
                         ((2 * (s & 63)) ^ ((jj & 7) << 4))) = f2bf(v);
          } else {
            int col = 64 + (jj - 128);                    // nope -> k dims 64..127
            *(ushort_t*)(kbuf + (bh * Sc + s) * 256 + ((2 * col) ^ ((s & 7) << 4))) = f2bf(v);
          }
        }
      }
    }
  }
}

// ---------------- broadcast k_rope into kbuf (swizzled byte layout) ----------------
__global__ void rope_fill(const ushort_t* __restrict__ comp, char* __restrict__ kbuf) {
  int i = blockIdx.x * 256 + threadIdx.x;  // over B*S*8 16-byte blocks
  if (i >= Bc * Sc * 8) return;
  int blk = i & 7;
  int m = i >> 3;
  int s = m & 2047, b = m >> 11;
  uint4 v = *(const uint4*)&comp[(size_t)m * 640 + 512 + blk * 8];
  int off = (blk * 16) ^ ((s & 7) << 4);
#pragma unroll
  for (int h = 0; h < Hc; h++) {
    *(uint4*)(kbuf + ((size_t)(b * Hc + h) * Sc + s) * 256 + off) = v;
  }
}

// ---------------- flash attention, SWAPPED QK^T: each lane owns one q-row ----------------
// block = (b,h,qtile of 64 rows), 4 waves x 16 rows; 2 barriers/tile.
// sc = mfma(K,Q): C col(l16)=q-row, C row(g16*4+r)=k-index -> softmax is lane-local.
__global__ __launch_bounds__(256, 4)
void attn_kernel(const ushort_t* __restrict__ qb, const char* __restrict__ kbuf,
                 const char* __restrict__ vtb, const ushort_t* __restrict__ m3,
                 ushort_t* __restrict__ attn_o)
{
  __shared__ __align__(16) char smem[40960];
  char* sK = smem;            // 16KB: 64 k-rows x 256B (swizzled)
  char* sV = smem + 16384;    // 16KB: 128 vd-rows x 128B (swizzled)
  char* sP = smem + 32768;    // 8KB: 4 waves x 16 q-rows x 128B (swizzled)
  const float scale2 = 0.12752081738040466f;  // 128^-0.5 / ln2
  int bid = blockIdx.x;
  bid = (bid & 7) * 128 + (bid >> 3);        // XCD-chunked swizzle (1024 % 8 == 0)
  int qt = bid & 31, bh = bid >> 5;
  int b = bh >> 4, h = bh & 15;
  int tid = threadIdx.x, wave = tid >> 6, lane = tid & 63;
  int l16 = lane & 15, g16 = lane >> 4;
  int sx = (l16 & 7) << 4;

  // Q fragments (B-operand: row = l16 = this lane's q-row)
  bf16x8 qf[4];
  int qrow = qt * 64 + wave * 16 + l16;      // lane's q-row (softmax row)
  {
    const ushort_t* qp = qb + (size_t)(b * Sc + qrow) * 2048 + h * 128 + g16 * 8;
#pragma unroll
    for (int kf = 0; kf < 4; kf++) qf[kf] = *(const bf16x8*)(qp + kf * 32);
  }

  float mrun = -3.0e38f, lrun = 0.f;         // per-lane scalars (q = qrow)
  f32x4 acco[8] = {};

  const char* kg = kbuf + (size_t)bh * Sc * 256;
  const char* vg = vtb + (size_t)bh * 524288;
  char* pB = sP + wave * 2048 + l16 * 128;
  const ushort8v* mq = (const ushort8v*)m3 + (size_t)qrow * 256 + g16 * 2;

  for (int kt = 0; kt < 32; kt++) {
    // stage K tile: 16KB linear (global bytes pre-swizzled)
#pragma unroll
    for (int it = 0; it < 4; it++)
      gload16(kg + kt * 16384 + it * 4096 + tid * 16, sK + it * 4096 + tid * 16);
    // stage V^T tile: 16KB, per-vd-row 128B chunks (global bytes pre-swizzled)
#pragma unroll
    for (int it = 0; it < 4; it++) {
      int l = it * 4096 + tid * 16;
      gload16(vg + (size_t)(l >> 7) * 4096 + kt * 128 + (l & 127), sV + l);
    }
    // mask fragments for this tile (coalesced 2x16B; hides under MFMA)
    ushort8v mv0 = mq[kt * 8];
    ushort8v mv1 = mq[kt * 8 + 1];
    __syncthreads();

    // scores (SWAPPED): sc[ni] = K(64 rows) . Q^T -> cols = q-rows
    f32x4 sc[4] = {};
    __builtin_amdgcn_s_setprio(1);
#pragma unroll
    for (int ni = 0; ni < 4; ni++) {
#pragma unroll
      for (int kf = 0; kf < 4; kf++) {
        bf16x8 kfr = *(const bf16x8*)(sK + (ni * 16 + l16) * 256 +
                                      ((kf * 64 + g16 * 16) ^ sx));
        sc[ni] = MFMA16(kfr, qf[kf], sc[ni], 0, 0, 0);
      }
    }
    __builtin_amdgcn_s_setprio(0);

    // lane-local softmax in exp2 domain: lane holds P[qrow][k = ni*16+g16*4+r]
#pragma unroll
    for (int ni = 0; ni < 4; ni++) {
      const ushort8v& mv = (ni < 2) ? mv0 : mv1;
      int base = (ni & 1) * 4;
#pragma unroll
      for (int r = 0; r < 4; r++)
        sc[ni][r] = sc[ni][r] * scale2 + bf2f(mv[base + r]);
    }
    float mx = fmaxf(fmaxf(fmaxf(sc[0][0], sc[0][1]), fmaxf(sc[0][2], sc[0][3])),
                     fmaxf(fmaxf(sc[1][0], sc[1][1]), fmaxf(sc[1][2], sc[1][3])));
    mx = fmaxf(mx, fmaxf(fmaxf(fmaxf(sc[2][0], sc[2][1]), fmaxf(sc[2][2], sc[2][3])),
                         fmaxf(fmaxf(sc[3][0], sc[3][1]), fmaxf(sc[3][2], sc[3][3]))));
    mx = fmaxf(mx, __shfl_xor(mx, 16));
    mx = fmaxf(mx, __shfl_xor(mx, 32));
    if (!__all(mx <= mrun + 11.0f)) {       // T13 defer-max (rare path)
      float mnew = fmaxf(mrun, mx);
      float corr = __builtin_amdgcn_exp2f(mrun - mnew);
      lrun *= corr;
      mrun = mnew;
      // acco rows are q = base+g16*4+r -> fetch that row's corr
      float cr0 = __shfl(corr, g16 * 4 + 0);
      float cr1 = __shfl(corr, g16 * 4 + 1);
      float cr2 = __shfl(corr, g16 * 4 + 2);
      float cr3 = __shfl(corr, g16 * 4 + 3);
#pragma unroll
      for (int ni = 0; ni < 8; ni++) {
        acco[ni][0] *= cr0; acco[ni][1] *= cr1;
        acco[ni][2] *= cr2; acco[ni][3] *= cr3;
      }
    }
    float rs = 0.f;
#pragma unroll
    for (int ni = 0; ni < 4; ni++) {
      float p0 = __builtin_amdgcn_exp2f(sc[ni][0] - mrun);
      float p1 = __builtin_amdgcn_exp2f(sc[ni][1] - mrun);
      float p2 = __builtin_amdgcn_exp2f(sc[ni][2] - mrun);
      float p3 = __builtin_amdgcn_exp2f(sc[ni][3] - mrun);
      rs += (p0 + p1) + (p2 + p3);
      uint2 w;
      w.x = cvtpk(p0, p1);
      w.y = cvtpk(p2, p3);
      *(uint2*)(pB + ((ni * 32 + g16 * 8) ^ sx)) = w;   // k contiguous with r
    }
    lrun += rs;   // lane-partial; combined in epilogue

    // PV: acco += P(16x64) . V(64x128)   (P wave-private -> no barrier)
    __builtin_amdgcn_s_setprio(1);
#pragma unroll
    for (int kf = 0; kf < 2; kf++) {
      bf16x8 pa = *(const bf16x8*)(pB + ((kf * 64 + g16 * 16) ^ sx));
#pragma unroll
      for (int ni = 0; ni < 8; ni++) {
        bf16x8 vf = *(const bf16x8*)(sV + (ni * 16 + l16) * 128 +
                                     ((kf * 64 + g16 * 16) ^ sx));
        acco[ni] = MFMA16(pa, vf, acco[ni], 0, 0, 0);
      }
    }
    __builtin_amdgcn_s_setprio(0);

    __syncthreads();   // all waves done reading sK/sV before next stage
  }

  // epilogue: combine lane-partial l (dups across g16), redistribute to C-row order
  lrun += __shfl_xor(lrun, 16);
  lrun += __shfl_xor(lrun, 32);
  float lr[4];
#pragma unroll
  for (int r = 0; r < 4; r++) lr[r] = __shfl(lrun, g16 * 4 + r);
#pragma unroll
  for (int ni = 0; ni < 8; ni++) {
#pragma unroll
    for (int r = 0; r < 4; r++) {
      int qr = qt * 64 + wave * 16 + g16 * 4 + r;
      int col = ni * 16 + l16;
      float o = acco[ni][r] / lr[r];
      attn_o[(size_t)(b * Sc + qr) * 2048 + h * 128 + col] = f2bf(o);
    }
  }
}

extern "C" void kernel_launch(void* const* d_in, const int* in_sizes, int n_in,
                              void* d_out, int out_size, void* d_ws, size_t ws_size,
                              hipStream_t stream) {
  const float* x    = (const float*)d_in[0];
  const float* mask = (const float*)d_in[1];
  const float* Wkvd = (const float*)d_in[2];
  const float* Wkvu = (const float*)d_in[3];
  const float* Wq   = (const float*)d_in[4];
  const float* Wout = (const float*)d_in[5];

  char* ws = (char*)d_ws;
  size_t off = 0;
  auto alloc = [&](size_t bytes) { char* p = ws + off; off += (bytes + 255) & ~(size_t)255; return p; };
  ushort_t* xb   = (ushort_t*)alloc((size_t)4096 * 2048 * 2);
  ushort_t* wkvd = (ushort_t*)alloc((size_t)640 * 2048 * 2);
  ushort_t* wq   = (ushort_t*)alloc((size_t)2048 * 2048 * 2);
  ushort_t* wkvu = (ushort_t*)alloc((size_t)3072 * 512 * 2);
  ushort_t* wout = (ushort_t*)alloc((size_t)2048 * 2048 * 2);
  ushort_t* comp = (ushort_t*)alloc((size_t)4096 * 640 * 2);
  ushort_t* qbuf = (ushort_t*)alloc((size_t)4096 * 2048 * 2);
  char*     kbuf = alloc((size_t)Bc * Hc * Sc * 256);
  char*     vtb  = alloc((size_t)Bc * Hc * 524288);
  ushort_t* attn_o = xb;   // xb dead after q-GEMM; reuse
  ushort_t* m3 = wq;       // wq dead after q-GEMM; reuse (8MB)

  // all casts in one launch
  cast_all<<<19200, 256, 0, stream>>>(x, Wq, Wkvu, Wout, Wkvd, xb, wq, wkvu, wout, wkvd);

  // compressed = x . W_kv_down^T  (N padded 576->640)
  gemm_bt<0><<<32 * 5, 256, 0, stream>>>(xb, 2048, wkvd, 2048, comp, 640, 4096, 640, 2048, nullptr, nullptr);
  // q = x . W_q^T
  gemm_bt<0><<<32 * 16, 256, 0, stream>>>(xb, 2048, wq, 2048, qbuf, 2048, 4096, 2048, 2048, nullptr, nullptr);
  // mask -> swapped fragment order bf16 * (1/ln2)  (after q-GEMM: m3 overlays wq)
  mask_rearrange<<<2048, 256, 0, stream>>>(mask, m3);
  // kv_exp = kv_c . W_kv_up^T, scattered into vT(swizzled) + kbuf(nope, swizzled)
  gemm_bt<1><<<32 * 24, 256, 0, stream>>>(comp, 640, wkvu, 512, nullptr, 0, 4096, 3072, 512, vtb, kbuf);
  // k_rope broadcast into kbuf (swizzled)
  rope_fill<<<32768 / 256, 256, 0, stream>>>(comp, kbuf);
  // flash attention (swapped QK^T)
  attn_kernel<<<1024, 256, 0, stream>>>(qbuf, kbuf, vtb, m3, attn_o);
  // out = attn . W_out^T (fp32 store)
  gemm_bt<2><<<32 * 16, 256, 0, stream>>>(attn_o, 2048, wout, 2048, d_out, 2048, 4096, 2048, 2048, nullptr, nullptr);
}

// Round 6
// 288.927 us; speedup vs baseline: 1.8440x; 1.0181x over previous
//
#include <hip/hip_runtime.h>
#include <hip/hip_bf16.h>
#include <stdint.h>

typedef __bf16 bf16x8 __attribute__((ext_vector_type(8)));
typedef float f32x4 __attribute__((ext_vector_type(4)));
typedef float f32x16 __attribute__((ext_vector_type(16)));
typedef uint32_t u32x4 __attribute__((ext_vector_type(4)));
typedef unsigned short ushort_t;
typedef unsigned short ushort8v __attribute__((ext_vector_type(8)));

#define MFMA16 __builtin_amdgcn_mfma_f32_16x16x32_bf16
#define MFMA32 __builtin_amdgcn_mfma_f32_32x32x16_bf16

static constexpr int Bc = 2, Sc = 2048, Ec = 2048, Hc = 16;

__device__ __forceinline__ void gload16(const void* g, void* l) {
  __builtin_amdgcn_global_load_lds(
      (const __attribute__((address_space(1))) void*)g,
      (__attribute__((address_space(3))) void*)l, 16, 0, 0);
}

__device__ __forceinline__ ushort_t f2bf(float f) {
  uint32_t u = __float_as_uint(f);
  uint32_t r = (u + 0x7fffu + ((u >> 16) & 1u)) >> 16;
  return (ushort_t)r;
}
__device__ __forceinline__ float bf2f(ushort_t u) {
  return __uint_as_float((uint32_t)u << 16);
}
__device__ __forceinline__ uint32_t cvtpk(float a, float b) {
  uint32_t d;
  asm("v_cvt_pk_bf16_f32 %0, %1, %2" : "=v"(d) : "v"(a), "v"(b));
  return d;
}
// exchange: a[lanes 32..63] <-> b[lanes 0..31]
__device__ __forceinline__ void plswap(uint32_t& a, uint32_t& b) {
  asm("v_permlane32_swap_b32 %0, %1" : "+v"(a), "+v"(b));
}

// ---------------- fused casts: all 5 weight/x tensors in one launch ----------------
__global__ void cast_all(const float* __restrict__ x, const float* __restrict__ Wq,
                         const float* __restrict__ Wkvu, const float* __restrict__ Wout,
                         const float* __restrict__ Wkvd,
                         ushort_t* __restrict__ xb, ushort_t* __restrict__ wq,
                         ushort_t* __restrict__ wkvu, ushort_t* __restrict__ wout,
                         ushort_t* __restrict__ wkvd) {
  int i = blockIdx.x * 256 + threadIdx.x;
  const float* src;
  ushort_t* dst;
  int j;
  if (i < 2097152) { src = x; dst = xb; j = i; }
  else if (i < 3145728) { src = Wq; dst = wq; j = i - 2097152; }
  else if (i < 3538944) { src = Wkvu; dst = wkvu; j = i - 3145728; }
  else if (i < 4587520) { src = Wout; dst = wout; j = i - 3538944; }
  else {
    j = i - 4587520;                      // wkvd with row pad 576->640
    int row = j >> 9, col4 = j & 511;
    ushort4 o;
    if (row < 576) {
      float4 v = ((const float4*)Wkvd)[row * 512 + col4];
      o.x = f2bf(v.x); o.y = f2bf(v.y); o.z = f2bf(v.z); o.w = f2bf(v.w);
    } else { o.x = 0; o.y = 0; o.z = 0; o.w = 0; }
    ((ushort4*)wkvd)[j] = o;
    return;
  }
  float4 v = ((const float4*)src)[j];
  ushort4 o;
  o.x = f2bf(v.x); o.y = f2bf(v.y); o.z = f2bf(v.z); o.w = f2bf(v.w);
  ((ushort4*)dst)[j] = o;
}

// ---------------- mask rearrange for 32x32 swapped layout ----------------
// ushort8 unit index u = q*256 + kt*8 + kblk*4 + half*2 + rr
// element j: value = mask[q][kt*64 + kblk*32 + 4*half + (j&3) + 8*(2*rr+(j>>2))] / ln2
__global__ void mask_rearrange(const float* __restrict__ mask, ushort_t* __restrict__ m4) {
  const float INVLN2 = 1.4426950408889634f;
  int i = blockIdx.x * 256 + threadIdx.x;   // 524288 units
  if (i >= 524288) return;
  int rr = i & 1, half = (i >> 1) & 1, kblk = (i >> 2) & 1, kt = (i >> 3) & 31, q = i >> 8;
  const float* src = mask + (size_t)q * 2048 + kt * 64 + kblk * 32 + half * 4 + rr * 16;
  float4 a = *(const float4*)src;         // j=0..3
  float4 c = *(const float4*)(src + 8);   // j=4..7
  ushort8v o;
  o[0] = f2bf(a.x * INVLN2); o[1] = f2bf(a.y * INVLN2);
  o[2] = f2bf(a.z * INVLN2); o[3] = f2bf(a.w * INVLN2);
  o[4] = f2bf(c.x * INVLN2); o[5] = f2bf(c.y * INVLN2);
  o[6] = f2bf(c.z * INVLN2); o[7] = f2bf(c.w * INVLN2);
  ((ushort8v*)m4)[i] = o;
}

// ---------------- GEMM: C[m][n] = sum_k A[m][k]*B[n][k], 128x128x32 tiles ----------------
template<int MODE>
__global__ __launch_bounds__(256, 2)
void gemm_bt(const ushort_t* __restrict__ A, int lda,
             const ushort_t* __restrict__ Bm, int ldb,
             void* __restrict__ Cout, int ldc,
             int M, int N, int K,
             char* __restrict__ vtb, char* __restrict__ kbuf)
{
  __shared__ __align__(16) ushort_t sA[128 * 32];
  __shared__ __align__(16) ushort_t sB[128 * 32];
  int tid = threadIdx.x;
  int nTn = N >> 7;
  int bid = blockIdx.x;
  int chunk = gridDim.x >> 3;                       // grids are %8==0 -> bijective
  bid = (bid & 7) * chunk + (bid >> 3);             // XCD-chunked swizzle
  int tm = bid / nTn, tn = bid - tm * nTn;
  int wave = tid >> 6, lane = tid & 63;
  int wm = (wave >> 1) << 6, wn = (wave & 1) << 6;
  int l16 = lane & 15, g16 = lane >> 4;
  f32x4 acc[4][4] = {};
  int srow = tid >> 2, scol = (tid & 3) << 3;
  const ushort_t* Ag = A + (size_t)(tm * 128 + srow) * lda + scol;
  const ushort_t* Bg = Bm + (size_t)(tn * 128 + srow) * ldb + scol;
  ushort_t* sAp = &sA[srow * 32 + scol];
  ushort_t* sBp = &sB[srow * 32 + scol];
  for (int kt = 0; kt < K; kt += 32) {
    gload16(Ag, sAp);
    gload16(Ag + (size_t)64 * lda, sAp + 64 * 32);
    gload16(Bg, sBp);
    gload16(Bg + (size_t)64 * ldb, sBp + 64 * 32);
    Ag += 32; Bg += 32;
    __syncthreads();
    bf16x8 af[4], bfr[4];
#pragma unroll
    for (int i = 0; i < 4; i++) af[i] = *(const bf16x8*)&sA[(wm + i * 16 + l16) * 32 + g16 * 8];
#pragma unroll
    for (int i = 0; i < 4; i++) bfr[i] = *(const bf16x8*)&sB[(wn + i * 16 + l16) * 32 + g16 * 8];
#pragma unroll
    for (int i = 0; i < 4; i++)
#pragma unroll
      for (int j = 0; j < 4; j++)
        acc[i][j] = MFMA16(af[i], bfr[j], acc[i][j], 0, 0, 0);
    __syncthreads();
  }
  // epilogue: C/D layout col=lane&15, row=(lane>>4)*4+r
#pragma unroll
  for (int i = 0; i < 4; i++) {
#pragma unroll
    for (int j = 0; j < 4; j++) {
#pragma unroll
      for (int r = 0; r < 4; r++) {
        int grow = tm * 128 + wm + i * 16 + g16 * 4 + r;
        int gcol = tn * 128 + wn + j * 16 + l16;
        float v = acc[i][j][r];
        if constexpr (MODE == 0) {
          ((ushort_t*)Cout)[(size_t)grow * ldc + gcol] = f2bf(v);
        } else if constexpr (MODE == 2) {
          ((float*)Cout)[(size_t)grow * ldc + gcol] = v;
        } else {
          int h = gcol / 192, jj = gcol - h * 192;
          int b = grow >> 11, s = grow & 2047;
          size_t bh = (size_t)(b * Hc + h);
          if (jj < 128) {
            // V^T, pre-swizzled for linear staging of 64-col tiles
            *(ushort_t*)(vtb + bh * 524288 + (size_t)jj * 4096 + ((s >> 6) * 128) +
                         ((2 * (s & 63)) ^ ((jj & 7) << 4))) = f2bf(v);
          } else {
            int col = 64 + (jj - 128);                    // nope -> k dims 64..127
            *(ushort_t*)(kbuf + (bh * Sc + s) * 256 + ((2 * col) ^ ((s & 7) << 4))) = f2bf(v);
          }
        }
      }
    }
  }
}

// ---------------- broadcast k_rope into kbuf (swizzled byte layout) ----------------
__global__ void rope_fill(const ushort_t* __restrict__ comp, char* __restrict__ kbuf) {
  int i = blockIdx.x * 256 + threadIdx.x;  // over B*S*8 16-byte blocks
  if (i >= Bc * Sc * 8) return;
  int blk = i & 7;
  int m = i >> 3;
  int s = m & 2047, b = m >> 11;
  uint4 v = *(const uint4*)&comp[(size_t)m * 640 + 512 + blk * 8];
  int off = (blk * 16) ^ ((s & 7) << 4);
#pragma unroll
  for (int h = 0; h < Hc; h++) {
    *(uint4*)(kbuf + ((size_t)(b * Hc + h) * Sc + s) * 256 + off) = v;
  }
}

// ---------------- flash attention, 32x32 MFMA + swapped QK^T + in-register P ----------------
// block = 128 threads = 2 waves x 32 q-rows (q-tile 64); KVBLK=64; LDS 32KB.
// sc = mfma32(K,Q): col(lane&31)=q, row(reg-pattern + 4*(lane>>5))=k -> softmax lane-local.
// P redistributed to PV A-frags via cvt_pk + permlane32_swap (no P LDS).
__global__ __launch_bounds__(128, 2)
void attn_kernel(const ushort_t* __restrict__ qb, const char* __restrict__ kbuf,
                 const char* __restrict__ vtb, const ushort_t* __restrict__ m4,
                 ushort_t* __restrict__ attn_o)
{
  __shared__ __align__(16) char smem[32768];
  char* sK = smem;            // 16KB: 64 k-rows x 256B (swizzled)
  char* sV = smem + 16384;    // 16KB: 128 vd-rows x 128B (swizzled)
  const float scale2 = 0.12752081738040466f;  // 128^-0.5 / ln2
  int bid = blockIdx.x;
  bid = (bid & 7) * 128 + (bid >> 3);        // XCD-chunked swizzle (1024 % 8 == 0)
  int qt = bid & 31, bh = bid >> 5;
  int b = bh >> 4, h = bh & 15;
  int tid = threadIdx.x, wave = tid >> 6, lane = tid & 63;
  int l32 = lane & 31, half = lane >> 5;
  int sx = (l32 & 7) << 4;
  int qbase = qt * 64 + wave * 32;

  // Q fragments (B-operand): col = q = l32, k = ks*16 + half*8 + e
  bf16x8 qf[8];
  {
    const ushort_t* qp = qb + (size_t)(b * Sc + qbase + l32) * 2048 + h * 128 + half * 8;
#pragma unroll
    for (int ks = 0; ks < 8; ks++) qf[ks] = *(const bf16x8*)(qp + ks * 16);
  }

  float mrun = -3.0e38f, lrun = 0.f;   // per-lane scalars for q = qbase + l32
  f32x16 acco[4] = {};                  // [vdblk]; rows = q reg-pattern, col = vd

  const char* kg = kbuf + (size_t)bh * 524288;
  const char* vg = vtb + (size_t)bh * 524288;
  const ushort8v* mq = (const ushort8v*)m4 + (size_t)(qbase + l32) * 256 + half * 2;

  for (int kt = 0; kt < 32; kt++) {
    // stage K tile: 16KB linear (global bytes pre-swizzled)
#pragma unroll
    for (int it = 0; it < 8; it++)
      gload16(kg + kt * 16384 + it * 2048 + tid * 16, sK + it * 2048 + tid * 16);
    // stage V^T tile: 16KB, per-vd-row 128B chunks (global bytes pre-swizzled)
#pragma unroll
    for (int it = 0; it < 8; it++) {
      int l = it * 2048 + tid * 16;
      gload16(vg + (size_t)(l >> 7) * 4096 + kt * 128 + (l & 127), sV + l);
    }
    // mask fragments for this tile (4 x 16B, coalesced; latency hides under stage)
    ushort8v mvv[4];
#pragma unroll
    for (int kb = 0; kb < 2; kb++)
#pragma unroll
      for (int rr = 0; rr < 2; rr++)
        mvv[kb * 2 + rr] = mq[kt * 8 + kb * 4 + rr];
    __syncthreads();

#pragma unroll
    for (int kblk = 0; kblk < 2; kblk++) {
      // QK^T (swapped): sc rows = k (32), cols = q (32)
      f32x16 sc = {};
      __builtin_amdgcn_s_setprio(1);
#pragma unroll
      for (int ks = 0; ks < 8; ks++) {
        bf16x8 kfr = *(const bf16x8*)(sK + (kblk * 32 + l32) * 256 +
                                      ((ks * 32 + half * 16) ^ sx));
        sc = MFMA32(kfr, qf[ks], sc, 0, 0, 0);
      }
      __builtin_amdgcn_s_setprio(0);

      // lane-local softmax: lane holds P[q=l32][k = (r&3)+8*(r>>2)+4*half + kblk*32]
#pragma unroll
      for (int r = 0; r < 16; r++)
        sc[r] = sc[r] * scale2 + bf2f(mvv[kblk * 2 + (r >> 3)][r & 7]);
      float mx = sc[0];
#pragma unroll
      for (int r = 1; r < 16; r++) mx = fmaxf(mx, sc[r]);
      mx = fmaxf(mx, __shfl_xor(mx, 32));
      if (!__all(mx <= mrun + 11.0f)) {       // T13 defer-max (rare)
        float mnew = fmaxf(mrun, mx);
        float corr = __builtin_amdgcn_exp2f(mrun - mnew);
        lrun *= corr; mrun = mnew;
#pragma unroll
        for (int r = 0; r < 16; r++) {
          float cr = __shfl(corr, (r & 3) + 8 * (r >> 2) + 4 * half);
#pragma unroll
          for (int vb = 0; vb < 4; vb++) acco[vb][r] *= cr;
        }
      }
      float rs = 0.f;
      uint32_t W[8];
#pragma unroll
      for (int m = 0; m < 4; m++) {
        float p0 = __builtin_amdgcn_exp2f(sc[4 * m + 0] - mrun);
        float p1 = __builtin_amdgcn_exp2f(sc[4 * m + 1] - mrun);
        float p2 = __builtin_amdgcn_exp2f(sc[4 * m + 2] - mrun);
        float p3 = __builtin_amdgcn_exp2f(sc[4 * m + 3] - mrun);
        rs += (p0 + p1) + (p2 + p3);
        W[2 * m] = cvtpk(p0, p1);
        W[2 * m + 1] = cvtpk(p2, p3);
      }
      lrun += rs;   // lane-partial (this half's k); combined in epilogue

      // redistribute P to PV A-frag layout: frag[k2] k = k2*16 + half*8 + e
      bf16x8 pf[2];
#pragma unroll
      for (int k2 = 0; k2 < 2; k2++) {
        uint32_t a0 = W[4 * k2 + 0], a1 = W[4 * k2 + 1];
        uint32_t b0 = W[4 * k2 + 2], b1 = W[4 * k2 + 3];
        plswap(a0, b0);
        plswap(a1, b1);
        u32x4 t; t[0] = a0; t[1] = a1; t[2] = b0; t[3] = b1;
        pf[k2] = __builtin_bit_cast(bf16x8, t);
      }

      // PV: acco[vb] += P(32q x 32k) . V(32k x 128vd)
      __builtin_amdgcn_s_setprio(1);
#pragma unroll
      for (int k2 = 0; k2 < 2; k2++)
#pragma unroll
        for (int vb = 0; vb < 4; vb++) {
          bf16x8 vf = *(const bf16x8*)(sV + (vb * 32 + l32) * 128 +
                                       ((kblk * 64 + k2 * 32 + half * 16) ^ sx));
          acco[vb] = MFMA32(pf[k2], vf, acco[vb], 0, 0, 0);
        }
      __builtin_amdgcn_s_setprio(0);
    }

    __syncthreads();   // all waves done reading sK/sV before next stage
  }

  // epilogue: combine half-partial l, divide, store
  lrun += __shfl_xor(lrun, 32);
#pragma unroll
  for (int r = 0; r < 16; r++) {
    int rowq = (r & 3) + 8 * (r >> 2) + 4 * half;
    float lr = __shfl(lrun, rowq);
    float inv = 1.0f / lr;
    int qrow = qbase + rowq;
    ushort_t* op = attn_o + (size_t)(b * Sc + qrow) * 2048 + h * 128 + l32;
#pragma unroll
    for (int vb = 0; vb < 4; vb++)
      op[vb * 32] = f2bf(acco[vb][r] * inv);
  }
}

extern "C" void kernel_launch(void* const* d_in, const int* in_sizes, int n_in,
                              void* d_out, int out_size, void* d_ws, size_t ws_size,
                              hipStream_t stream) {
  const float* x    = (const float*)d_in[0];
  const float* mask = (const float*)d_in[1];
  const float* Wkvd = (const float*)d_in[2];
  const float* Wkvu = (const float*)d_in[3];
  const float* Wq   = (const float*)d_in[4];
  const float* Wout = (const float*)d_in[5];

  char* ws = (char*)d_ws;
  size_t off = 0;
  auto alloc = [&](size_t bytes) { char* p = ws + off; off += (bytes + 255) & ~(size_t)255; return p; };
  ushort_t* xb   = (ushort_t*)alloc((size_t)4096 * 2048 * 2);
  ushort_t* wkvd = (ushort_t*)alloc((size_t)640 * 2048 * 2);
  ushort_t* wq   = (ushort_t*)alloc((size_t)2048 * 2048 * 2);
  ushort_t* wkvu = (ushort_t*)alloc((size_t)3072 * 512 * 2);
  ushort_t* wout = (ushort_t*)alloc((size_t)2048 * 2048 * 2);
  ushort_t* comp = (ushort_t*)alloc((size_t)4096 * 640 * 2);
  ushort_t* qbuf = (ushort_t*)alloc((size_t)4096 * 2048 * 2);
  char*     kbuf = alloc((size_t)Bc * Hc * Sc * 256);
  char*     vtb  = alloc((size_t)Bc * Hc * 524288);
  ushort_t* attn_o = xb;   // xb dead after q-GEMM; reuse
  ushort_t* m4 = wq;       // wq dead after q-GEMM; reuse (8MB)

  // all casts in one launch
  cast_all<<<19200, 256, 0, stream>>>(x, Wq, Wkvu, Wout, Wkvd, xb, wq, wkvu, wout, wkvd);

  // compressed = x . W_kv_down^T  (N padded 576->640)
  gemm_bt<0><<<32 * 5, 256, 0, stream>>>(xb, 2048, wkvd, 2048, comp, 640, 4096, 640, 2048, nullptr, nullptr);
  // q = x . W_q^T
  gemm_bt<0><<<32 * 16, 256, 0, stream>>>(xb, 2048, wq, 2048, qbuf, 2048, 4096, 2048, 2048, nullptr, nullptr);
  // mask -> 32x32 swapped fragment order bf16 * (1/ln2)  (after q-GEMM: m4 overlays wq)
  mask_rearrange<<<2048, 256, 0, stream>>>(mask, m4);
  // kv_exp = kv_c . W_kv_up^T, scattered into vT(swizzled) + kbuf(nope, swizzled)
  gemm_bt<1><<<32 * 24, 256, 0, stream>>>(comp, 640, wkvu, 512, nullptr, 0, 4096, 3072, 512, vtb, kbuf);
  // k_rope broadcast into kbuf (swizzled)
  rope_fill<<<32768 / 256, 256, 0, stream>>>(comp, kbuf);
  // flash attention (32x32 MFMA, in-register P)
  attn_kernel<<<1024, 128, 0, stream>>>(qbuf, kbuf, vtb, m4, attn_o);
  // out = attn . W_out^T (fp32 store)
  gemm_bt<2><<<32 * 16, 256, 0, stream>>>(attn_o, 2048, wout, 2048, d_out, 2048, 4096, 2048, 2048, nullptr, nullptr);
}